// Round 2
// 41602.426 us; speedup vs baseline: 1.2251x; 1.2251x over previous
//
#include <hip/hip_runtime.h>
#include <math.h>

// ---- workspace layout (float units) ----
#define WN_OFF    0          // 512*3072 filtered noise, [t][n]
#define THBUF_OFF 1572864    // 2 * 32*3072 fp32 tanh(h), [parity][b][n]
#define THT_OFF   1769472    // 2 * 3072*32 fp32 tanh(h) transposed, [parity][n][b]
#define XT_OFF    1966080    // 512*512 fp32 x transposed, [t][b*16+i]
#define BAR_OFF   2228224    // flags: 256 * 16 uints (64B spaced) + gen at [4096]
// ---- output layout (float units) ----
#define Y0_OFF    50331648
#define YR0_OFF   50348032
#define MASTER    255

// ---- dynamic LDS layout (float units) ----
#define L_W      0            // 16*1028 = 16448
#define L_TH     16448        // 2*32*260 = 16640
#define L_COUP   33088        // 1024 (aux WGs alias this as auxb)
#define L_WIH    34112        // 256
#define L_HBUF   34368        // 2048
#define L_RED    36416        // 1024
#define L_CI     37440        // 16
#define L_GIDX   37456        // 208 ints
#define L_QLJ    37664        // 16 ints
#define L_QLQ    37680        // 16 ints
#define L_NQ     37696        // 1 int
#define SMEM_FLOATS 37760
#define SMEM_BYTES  (SMEM_FLOATS * 4)

typedef float fx4 __attribute__((ext_vector_type(4)));

__device__ __forceinline__ void nt_store_f4(float* p, float4 v) {
  fx4 w; w.x = v.x; w.y = v.y; w.z = v.z; w.w = v.w;
  __builtin_nontemporal_store(w, (fx4*)p);
}

__global__ void prep1(const float* __restrict__ x,
                      const float* __restrict__ h0,
                      float* __restrict__ ws) {
  int i = blockIdx.x * blockDim.x + threadIdx.x;
  const int stride = gridDim.x * blockDim.x;
  const int NXT = 512 * 512;
  const int NTH0 = 32 * 3072;
  const int NBAR = 4097;
  for (; i < NXT + NTH0 + NBAR; i += stride) {
    if (i < NXT) {
      int t = i >> 9, bi = i & 511;
      ws[XT_OFF + i] = x[bi * 512 + t];
    } else if (i < NXT + NTH0) {
      int e = i - NXT;
      int b = e / 3072, n = e - b * 3072;
      float v = tanhf(h0[e]);
      ws[THBUF_OFF + e] = v;
      ws[THT_OFF + n * 32 + b] = v;
    } else {
      ((unsigned*)(ws + BAR_OFF))[i - (NXT + NTH0)] = 0u;
    }
  }
}

__global__ void prep2(const float* __restrict__ iwn,
                      float* __restrict__ ws) {
  int n = blockIdx.x * blockDim.x + threadIdx.x;
  if (n >= 3072) return;
  const float s10 = sqrtf(10.0f);
  const float a = expf(-0.1f);
  float prev = s10 * iwn[n * 512];
  ws[WN_OFF + n] = 0.01f * prev;
  for (int t = 1; t < 512; ++t) {
    float cur = s10 * iwn[n * 512 + t];
    prev = cur + (prev - cur) * a;
    ws[WN_OFF + t * 3072 + n] = 0.01f * prev;
  }
}

// ---- coherent (agent-scope, relaxed) access helpers ----
// Relaxed agent-scope atomics operate at the device-coherent point (LLC)
// WITHOUT any L2 writeback/invalidate. All cross-WG data (th buffers,
// barrier flags) goes through these; everything else stays L2-cached.
__device__ __forceinline__ float4 ldc_f4(const float* p) {
  unsigned long long lo = __hip_atomic_load((const unsigned long long*)p,
                                            __ATOMIC_RELAXED, __HIP_MEMORY_SCOPE_AGENT);
  unsigned long long hi = __hip_atomic_load((const unsigned long long*)(p + 2),
                                            __ATOMIC_RELAXED, __HIP_MEMORY_SCOPE_AGENT);
  float4 r;
  r.x = __uint_as_float((unsigned)lo);
  r.y = __uint_as_float((unsigned)(lo >> 32));
  r.z = __uint_as_float((unsigned)hi);
  r.w = __uint_as_float((unsigned)(hi >> 32));
  return r;
}
__device__ __forceinline__ float ldc_f1(const float* p) {
  return __uint_as_float(__hip_atomic_load((const unsigned*)p,
                                           __ATOMIC_RELAXED, __HIP_MEMORY_SCOPE_AGENT));
}
__device__ __forceinline__ void stc_f1(float* p, float v) {
  __hip_atomic_store((unsigned*)p, __float_as_uint(v),
                     __ATOMIC_RELAXED, __HIP_MEMORY_SCOPE_AGENT);
}

// Fence-free flag barrier: all cross-WG data moved via coherent atomics,
// so no release/acquire cache maintenance (buffer_wbl2/buffer_inv) needed.
// Each thread drains its own stores (vmcnt(0)) before the WG joins, then
// tid0 publishes the flag relaxed; master aggregates and publishes gen.
__device__ __forceinline__ void flagBarrier(unsigned* flags, unsigned* gen,
                                            int g, int tid, unsigned tv) {
  asm volatile("s_waitcnt vmcnt(0)" ::: "memory");
  __syncthreads();
  if (tid == 0)
    __hip_atomic_store(&flags[g * 16], tv, __ATOMIC_RELAXED, __HIP_MEMORY_SCOPE_AGENT);
  if (g == MASTER) {
    while (__hip_atomic_load(&flags[tid * 16], __ATOMIC_RELAXED,
                             __HIP_MEMORY_SCOPE_AGENT) < tv)
      __builtin_amdgcn_s_sleep(1);
    __syncthreads();
    if (tid == 0)
      __hip_atomic_store(gen, tv, __ATOMIC_RELAXED, __HIP_MEMORY_SCOPE_AGENT);
  } else {
    if (tid == 0) {
      while (__hip_atomic_load(gen, __ATOMIC_RELAXED,
                               __HIP_MEMORY_SCOPE_AGENT) < tv)
        __builtin_amdgcn_s_sleep(1);
    }
    __syncthreads();
  }
}

#define LOADPF(c_) do { \
  const float* src_ = thmod + (c_) * 256; \
  _Pragma("unroll") \
  for (int i_ = 0; i_ < 8; ++i_) { \
    int e_ = i_ * 1024 + tid * 4; \
    pf[i_] = ldc_f4(src_ + (e_ >> 8) * 3072 + (e_ & 255)); \
  } } while (0)

#define WRITEBUF(c_) do { \
  float* dst_ = th_base + ((c_) & 1) * 8320; \
  _Pragma("unroll") \
  for (int i_ = 0; i_ < 8; ++i_) { \
    int e_ = i_ * 1024 + tid * 4; \
    *(float4*)(dst_ + (e_ >> 8) * 260 + (e_ & 255)) = pf[i_]; \
  } } while (0)

#define COMPUTE_CHUNK(c_) do { \
  const float* tb_ = th_base + ((c_) & 1) * 8320; \
  const float* t0_ = tb_ + bb * 260 + kb; \
  const float* t1_ = t0_ + 4160; \
  const float* w0_ = W_lds + jg * 1028 + (c_) * 256 + kb; \
  const float* w1_ = w0_ + 8224; \
  _Pragma("unroll") \
  for (int kk = 0; kk < 128; kk += 8) { \
    float4 wa0 = *(const float4*)(w0_ + kk); \
    float4 wa1 = *(const float4*)(w0_ + kk + 4); \
    float4 wb0 = *(const float4*)(w1_ + kk); \
    float4 wb1 = *(const float4*)(w1_ + kk + 4); \
    float4 t0a = *(const float4*)(t0_ + kk); \
    float4 t0b = *(const float4*)(t0_ + kk + 4); \
    float4 t1a = *(const float4*)(t1_ + kk); \
    float4 t1b = *(const float4*)(t1_ + kk + 4); \
    acc00 += wa0.x*t0a.x + wa0.y*t0a.y + wa0.z*t0a.z + wa0.w*t0a.w \
           + wa1.x*t0b.x + wa1.y*t0b.y + wa1.z*t0b.z + wa1.w*t0b.w; \
    acc01 += wa0.x*t1a.x + wa0.y*t1a.y + wa0.z*t1a.z + wa0.w*t1a.w \
           + wa1.x*t1b.x + wa1.y*t1b.y + wa1.z*t1b.z + wa1.w*t1b.w; \
    acc10 += wb0.x*t0a.x + wb0.y*t0a.y + wb0.z*t0a.z + wb0.w*t0a.w \
           + wb1.x*t0b.x + wb1.y*t0b.y + wb1.z*t0b.z + wb1.w*t0b.w; \
    acc11 += wb0.x*t1a.x + wb0.y*t1a.y + wb0.z*t1a.z + wb0.w*t1a.w \
           + wb1.x*t1b.x + wb1.y*t1b.y + wb1.z*t1b.z + wb1.w*t1b.w; \
  } } while (0)

__global__ void __launch_bounds__(256, 1) rnn_main(
    const float* __restrict__ Wih,
    const float* __restrict__ W11,
    const float* __restrict__ W22,
    const float* __restrict__ W33,
    const float* __restrict__ W12,
    const float* __restrict__ W23,
    const float* __restrict__ Who,
    const float* __restrict__ Whc2,
    const float* __restrict__ Wr1,
    const float* __restrict__ Wr2,
    const float* __restrict__ Wr3,
    const int* __restrict__ id12_1, const int* __restrict__ id12_2,
    const int* __restrict__ id23_2, const int* __restrict__ id23_3,
    const float* __restrict__ ctx,
    const float* __restrict__ h0,
    float* __restrict__ ws,
    float* __restrict__ out) {

  extern __shared__ float smem[];
  float* W_lds   = smem + L_W;
  float* th_base = smem + L_TH;
  float* coupf   = smem + L_COUP;
  float* Wih_lds = smem + L_WIH;
  float* Hbuf    = smem + L_HBUF;
  float* redsc   = smem + L_RED;
  float* ci16    = smem + L_CI;
  int* gidx_lds  = (int*)(smem + L_GIDX);
  int* ql_j      = (int*)(smem + L_QLJ);
  int* ql_q      = (int*)(smem + L_QLQ);
  int* nq_sp     = (int*)(smem + L_NQ);

  const int g = blockIdx.x;
  const int tid = threadIdx.x;
  unsigned* flags = (unsigned*)(ws + BAR_OFF);
  unsigned* gen = flags + 4096;
  const int mmod = (g < 192) ? (g >> 6) : 0;
  const int loc0 = (g & 63) * 16;
  const int bb = tid & 15;
  const int jg = (tid >> 4) & 7;
  const int kh = tid >> 7;
  const int kb = kh * 128;
  float h00 = 0.f, h01 = 0.f, h10 = 0.f, h11 = 0.f;

  if (g < 192) {
    const float* Wsrc = (mmod == 0) ? W11 : ((mmod == 1) ? W22 : W33);
    // stage W slice (16 x 1024 fp32) into LDS once
    #pragma unroll
    for (int i = 0; i < 16; ++i) {
      float4 v = *(const float4*)&Wsrc[(size_t)(loc0 + i) * 1024 + tid * 4];
      *(float4*)&W_lds[i * 1028 + tid * 4] = v;
    }
    if (mmod == 0) {
      Wih_lds[tid] = Wih[(loc0 + (tid >> 4)) * 16 + (tid & 15)];
    }
    if (mmod == 1 && tid < 16) {
      ci16[tid] = ctx[0] * Whc2[(loc0 + tid) * 2];
    }
    if (mmod != 0 && tid < 205) {
      const int* gsrc = (mmod == 1) ? id12_1 : id23_2;
      gidx_lds[tid] = gsrc[tid];
    }
    if (tid == 0) {
      int cnt = 0;
      if (mmod != 0) {
        const int* scat = (mmod == 1) ? id12_2 : id23_3;
        for (int q = 0; q < 205; ++q) {
          int jj = scat[q] - loc0;
          if (jj >= 0 && jj < 16) { ql_j[cnt] = jj; ql_q[cnt] = q; ++cnt; }
        }
      }
      *nq_sp = cnt;
    }
    if (!kh) {
      int gn0 = mmod * 1024 + loc0 + jg;
      h00 = h0[bb * 3072 + gn0];
      h01 = h0[(bb + 16) * 3072 + gn0];
      h10 = h0[bb * 3072 + gn0 + 8];
      h11 = h0[(bb + 16) * 3072 + gn0 + 8];
    }
  }
  __syncthreads();

  #pragma unroll 1
  for (int t = 0; t < 512; ++t) {
    const int p = t & 1;
    const float* thbuf_p = ws + THBUF_OFF + (size_t)p * 98304;
    float*       thbuf_n = ws + THBUF_OFF + (size_t)(p ^ 1) * 98304;
    const float* thT_p   = ws + THT_OFF + (size_t)p * 98304;
    float*       thT_n   = ws + THT_OFF + (size_t)(p ^ 1) * 98304;

    if (g < 192) {
      const float* thmod = thbuf_p + mmod * 1024;
      float4 pf[8];
      // zero coupling staging + prefetch chunk 0
      *(float4*)&coupf[tid * 4] = make_float4(0.f, 0.f, 0.f, 0.f);
      LOADPF(0);
      __syncthreads();
      // ---- sparse couplings ----
      if (mmod != 0) {
        const int ntask = *nq_sp * 64;
        const float* Wsp = (mmod == 1) ? W12 : W23;
        const int rbase = (mmod == 1) ? 0 : 1024;
        for (int task = tid; task < ntask; task += 256) {
          int kh2 = task & 1;
          int b = (task >> 1) & 31;
          int qi = task >> 6;
          int q = ql_q[qi], jj = ql_j[qi];
          int p0 = kh2 ? 103 : 0;
          int p1 = kh2 ? 205 : 103;
          float v = 0.0f;
          for (int pp = p0; pp < p1; ++pp) {
            v += Wsp[q * 205 + pp] * ldc_f1(&thT_p[(rbase + gidx_lds[pp]) * 32 + b]);
          }
          coupf[kh2 * 512 + jj * 32 + b] = v;
        }
      }
      WRITEBUF(0);
      // ---- main GEMM: W from LDS, th double-buffered ----
      float acc00 = 0.f, acc01 = 0.f, acc10 = 0.f, acc11 = 0.f;
      #pragma unroll 1
      for (int c = 0; c < 4; ++c) {
        __syncthreads();
        if (c < 3) LOADPF(c + 1);
        COMPUTE_CHUNK(c);
        if (c < 3) WRITEBUF(c + 1);
      }
      __syncthreads();
      if (kh) {
        int l = (tid - 128) * 4;
        redsc[l] = acc00; redsc[l + 1] = acc01;
        redsc[l + 2] = acc10; redsc[l + 3] = acc11;
      }
      __syncthreads();
      if (!kh) {
        acc00 += redsc[tid * 4];     acc01 += redsc[tid * 4 + 1];
        acc10 += redsc[tid * 4 + 2]; acc11 += redsc[tid * 4 + 3];
        const float* xTt = ws + XT_OFF + t * 512;
        const float* wnt = ws + WN_OFF + t * 3072;
        float accs[4] = {acc00, acc01, acc10, acc11};
        float hs[4] = {h00, h01, h10, h11};
        #pragma unroll
        for (int js = 0; js < 2; ++js) {
          int j = jg + js * 8;
          int gn = mmod * 1024 + loc0 + j;
          #pragma unroll
          for (int bs = 0; bs < 2; ++bs) {
            int b = bb + bs * 16;
            float dot = accs[js * 2 + bs];
            float extra;
            if (mmod == 0) {
              extra = 0.f;
              #pragma unroll
              for (int ii = 0; ii < 16; ++ii)
                extra += xTt[b * 16 + ii] * Wih_lds[j * 16 + ii];
            } else {
              float cp = coupf[j * 32 + b] + coupf[512 + j * 32 + b];
              extra = (mmod == 1) ? cp * ci16[j] : cp;
            }
            float hv = hs[js * 2 + bs];
            hv = hv + (dot + extra + wnt[gn] - hv) / 10.0f;
            hs[js * 2 + bs] = hv;
            float tv = tanhf(hv);
            stc_f1(&thbuf_n[b * 3072 + gn], tv);
            stc_f1(&thT_n[gn * 32 + b], tv);
            Hbuf[(j * 32 + b) * 4 + (t & 3)] = tv;
          }
        }
        h00 = hs[0]; h01 = hs[1]; h10 = hs[2]; h11 = hs[3];
      }
      if ((t & 3) == 3) {
        __syncthreads();
        #pragma unroll
        for (int r = 0; r < 2; ++r) {
          int o = tid * 2 + r;
          int j = o >> 5, b = o & 31;
          size_t gn = (size_t)(mmod * 1024 + loc0 + j);
          float4 v = *(const float4*)&Hbuf[o * 4];
          nt_store_f4(&out[((size_t)b * 3072 + gn) * 512 + (t - 3)], v);
        }
      }
    } else {
      // ---- aux WGs: y and yr readouts ----
      const int w = tid >> 6, lane = tid & 63;
      const int gw = (g - 192) * 4 + w;
      float* auxb = coupf;  // aux-only alias
      for (int s = 0; s < 4; ++s) {
        const int u = gw + s * 256;
        if (u >= 800) break;
        float a0 = 0.f, a1 = 0.f, a2 = 0.f, a3 = 0.f;
        if (u < 768) {
          const int mm = u >> 8;
          const int rem = u & 255;
          const int b = rem >> 3;
          const int rr0 = (rem & 7) * 4;
          const float* Wr = (mm == 0) ? Wr1 : ((mm == 1) ? Wr2 : Wr3);
          const float* trow = thbuf_p + b * 3072 + mm * 1024;
          #pragma unroll
          for (int it = 0; it < 4; ++it) {
            int k = it * 256 + lane * 4;
            float4 tv = ldc_f4(trow + k);
            float4 q0 = *(const float4*)&Wr[(rr0 + 0) * 1024 + k];
            float4 q1 = *(const float4*)&Wr[(rr0 + 1) * 1024 + k];
            float4 q2 = *(const float4*)&Wr[(rr0 + 2) * 1024 + k];
            float4 q3 = *(const float4*)&Wr[(rr0 + 3) * 1024 + k];
            a0 += tv.x*q0.x + tv.y*q0.y + tv.z*q0.z + tv.w*q0.w;
            a1 += tv.x*q1.x + tv.y*q1.y + tv.z*q1.z + tv.w*q1.w;
            a2 += tv.x*q2.x + tv.y*q2.y + tv.z*q2.z + tv.w*q2.w;
            a3 += tv.x*q3.x + tv.y*q3.y + tv.z*q3.z + tv.w*q3.w;
          }
        } else {
          const int b = u - 768;
          const float* trow = thbuf_p + b * 3072 + 2048;
          #pragma unroll
          for (int it = 0; it < 4; ++it) {
            int k = it * 256 + lane * 4;
            float4 tv = ldc_f4(trow + k);
            float4 q0 = *(const float4*)&Who[k];
            a0 += tv.x*q0.x + tv.y*q0.y + tv.z*q0.z + tv.w*q0.w;
          }
        }
        #pragma unroll
        for (int off = 32; off > 0; off >>= 1) {
          a0 += __shfl_xor(a0, off);
          a1 += __shfl_xor(a1, off);
          a2 += __shfl_xor(a2, off);
          a3 += __shfl_xor(a3, off);
        }
        if (lane == 0) {
          int base = ((w * 4 + s) * 4) * 4 + (t & 3);
          auxb[base] = tanhf(a0);
          if (u < 768) {
            auxb[base + 4]  = tanhf(a1);
            auxb[base + 8]  = tanhf(a2);
            auxb[base + 12] = tanhf(a3);
          }
        }
      }
      if ((t & 3) == 3) {
        __syncthreads();
        int s = lane >> 2, rv = lane & 3;
        if (lane < 16) {
          int u = gw + s * 256;
          if (u < 768) {
            int mm = u >> 8, rem = u & 255, b = rem >> 3, rr = (rem & 7) * 4 + rv;
            float4 v = *(const float4*)&auxb[((w * 4 + s) * 4 + rv) * 4];
            nt_store_f4(&out[(size_t)YR0_OFF + ((size_t)(b * 32 + rr) * 3 + mm) * 512 + (t - 3)], v);
          } else if (u < 800 && rv == 0) {
            float4 v = *(const float4*)&auxb[((w * 4 + s) * 4) * 4];
            nt_store_f4(&out[(size_t)Y0_OFF + (size_t)(u - 768) * 512 + (t - 3)], v);
          }
        }
      }
    }
    flagBarrier(flags, gen, g, tid, (unsigned)(t + 1));
  }
}

extern "C" void kernel_launch(void* const* d_in, const int* in_sizes, int n_in,
                              void* d_out, int out_size, void* d_ws, size_t ws_size,
                              hipStream_t stream) {
  (void)in_sizes; (void)n_in; (void)out_size; (void)ws_size;
  const float* x    = (const float*)d_in[0];
  const float* h0   = (const float*)d_in[1];
  const float* ctx  = (const float*)d_in[2];
  const float* iWN  = (const float*)d_in[3];
  const float* Wih  = (const float*)d_in[4];
  const float* W11  = (const float*)d_in[5];
  const float* W22  = (const float*)d_in[6];
  const float* W33  = (const float*)d_in[7];
  const float* W12  = (const float*)d_in[8];
  const float* W23  = (const float*)d_in[9];
  const float* Who  = (const float*)d_in[10];
  const float* Whc2 = (const float*)d_in[11];
  const float* Wr1  = (const float*)d_in[12];
  const float* Wr2  = (const float*)d_in[13];
  const float* Wr3  = (const float*)d_in[14];
  const int* id12_1 = (const int*)d_in[15];
  const int* id12_2 = (const int*)d_in[16];
  const int* id23_2 = (const int*)d_in[17];
  const int* id23_3 = (const int*)d_in[18];
  float* ws = (float*)d_ws;
  float* out = (float*)d_out;

  hipFuncSetAttribute(reinterpret_cast<const void*>(rnn_main),
                      hipFuncAttributeMaxDynamicSharedMemorySize, SMEM_BYTES);
  hipLaunchKernelGGL(prep1, dim3(512), dim3(256), 0, stream, x, h0, ws);
  hipLaunchKernelGGL(prep2, dim3(12), dim3(256), 0, stream, iWN, ws);
  hipLaunchKernelGGL(rnn_main, dim3(256), dim3(256), SMEM_BYTES, stream,
                     Wih, W11, W22, W33, W12, W23, Who, Whc2, Wr1, Wr2, Wr3,
                     id12_1, id12_2, id23_2, id23_3, ctx, h0, ws, out);
}

// Round 3
// 28695.560 us; speedup vs baseline: 1.7762x; 1.4498x over previous
//
#include <hip/hip_runtime.h>
#include <math.h>

// ---- workspace layout (float units) ----
#define WN_OFF    0          // 512*3072 filtered noise, [t][n]
#define THBUF_OFF 1572864    // 2 * 32*3072 fp32 tanh(h), [parity][b][n]
#define THT_OFF   1769472    // 2 * 3072*32 fp32 tanh(h) transposed, [parity][n][b]
#define XT_OFF    1966080    // 512*512 fp32 x transposed, [t][b*16+i]
#define BAR_OFF   2228224    // flags: 256*16 uints + gen: 32*16 uints at [4096..4607]
// ---- output layout (float units) ----
#define Y0_OFF    50331648
#define YR0_OFF   50348032
#define MASTER    255

// ---- dynamic LDS layout (float units) ----
#define L_W      0            // 16*1028 = 16448
#define L_TH     16448        // 2*32*260 = 16640 (2nd half doubles as sparse gather buf)
#define L_COUP   33088        // 1024 (aux WGs alias this as auxb)
#define L_WIH    34112        // 256
#define L_HBUF   34368        // 2048
#define L_RED    36416        // 1024
#define L_CI     37440        // 16
#define L_GIDX   37456        // 208 ints
#define L_QLJ    37664        // 16 ints
#define L_QLQ    37680        // 16 ints
#define L_NQ     37696        // 1 int
#define SMEM_FLOATS 37760
#define SMEM_BYTES  (SMEM_FLOATS * 4)

typedef float fx4 __attribute__((ext_vector_type(4)));

__device__ __forceinline__ void nt_store_f4(float* p, float4 v) {
  fx4 w; w.x = v.x; w.y = v.y; w.z = v.z; w.w = v.w;
  __builtin_nontemporal_store(w, (fx4*)p);
}

__global__ void prep1(const float* __restrict__ x,
                      const float* __restrict__ h0,
                      float* __restrict__ ws) {
  int i = blockIdx.x * blockDim.x + threadIdx.x;
  const int stride = gridDim.x * blockDim.x;
  const int NXT = 512 * 512;
  const int NTH0 = 32 * 3072;
  const int NBAR = 4608;
  for (; i < NXT + NTH0 + NBAR; i += stride) {
    if (i < NXT) {
      int t = i >> 9, bi = i & 511;
      ws[XT_OFF + i] = x[bi * 512 + t];
    } else if (i < NXT + NTH0) {
      int e = i - NXT;
      int b = e / 3072, n = e - b * 3072;
      float v = tanhf(h0[e]);
      ws[THBUF_OFF + e] = v;
      ws[THT_OFF + n * 32 + b] = v;
    } else {
      ((unsigned*)(ws + BAR_OFF))[i - (NXT + NTH0)] = 0u;
    }
  }
}

__global__ void prep2(const float* __restrict__ iwn,
                      float* __restrict__ ws) {
  int n = blockIdx.x * blockDim.x + threadIdx.x;
  if (n >= 3072) return;
  const float s10 = sqrtf(10.0f);
  const float a = expf(-0.1f);
  float prev = s10 * iwn[n * 512];
  ws[WN_OFF + n] = 0.01f * prev;
  for (int t = 1; t < 512; ++t) {
    float cur = s10 * iwn[n * 512 + t];
    prev = cur + (prev - cur) * a;
    ws[WN_OFF + t * 3072 + n] = 0.01f * prev;
  }
}

// ---- coherent (agent-scope, relaxed) access helpers ----
__device__ __forceinline__ float4 ldc_f4(const float* p) {
  unsigned long long lo = __hip_atomic_load((const unsigned long long*)p,
                                            __ATOMIC_RELAXED, __HIP_MEMORY_SCOPE_AGENT);
  unsigned long long hi = __hip_atomic_load((const unsigned long long*)(p + 2),
                                            __ATOMIC_RELAXED, __HIP_MEMORY_SCOPE_AGENT);
  float4 r;
  r.x = __uint_as_float((unsigned)lo);
  r.y = __uint_as_float((unsigned)(lo >> 32));
  r.z = __uint_as_float((unsigned)hi);
  r.w = __uint_as_float((unsigned)(hi >> 32));
  return r;
}
__device__ __forceinline__ float ldc_f1(const float* p) {
  return __uint_as_float(__hip_atomic_load((const unsigned*)p,
                                           __ATOMIC_RELAXED, __HIP_MEMORY_SCOPE_AGENT));
}
__device__ __forceinline__ void stc_f1(float* p, float v) {
  __hip_atomic_store((unsigned*)p, __float_as_uint(v),
                     __ATOMIC_RELAXED, __HIP_MEMORY_SCOPE_AGENT);
}

// Fence-free flag barrier. Gen is broadcast to 32 spaced lines; WG g polls
// line g>>3 (8 pollers/line) to avoid 255-reader contention on one line.
__device__ __forceinline__ void flagBarrier(unsigned* flags, unsigned* gen,
                                            int g, int tid, unsigned tv) {
  asm volatile("s_waitcnt vmcnt(0)" ::: "memory");
  __syncthreads();
  if (tid == 0)
    __hip_atomic_store(&flags[g * 16], tv, __ATOMIC_RELAXED, __HIP_MEMORY_SCOPE_AGENT);
  if (g == MASTER) {
    while (__hip_atomic_load(&flags[tid * 16], __ATOMIC_RELAXED,
                             __HIP_MEMORY_SCOPE_AGENT) < tv)
      __builtin_amdgcn_s_sleep(1);
    __syncthreads();
    if (tid < 32)
      __hip_atomic_store(&gen[tid * 16], tv, __ATOMIC_RELAXED, __HIP_MEMORY_SCOPE_AGENT);
  } else {
    if (tid == 0) {
      while (__hip_atomic_load(&gen[(g >> 3) * 16], __ATOMIC_RELAXED,
                               __HIP_MEMORY_SCOPE_AGENT) < tv)
        __builtin_amdgcn_s_sleep(1);
    }
    __syncthreads();
  }
}

#define LOADPF(c_) do { \
  const float* src_ = thmod + (c_) * 256; \
  _Pragma("unroll") \
  for (int i_ = 0; i_ < 8; ++i_) { \
    int e_ = i_ * 1024 + tid * 4; \
    pf[i_] = ldc_f4(src_ + (e_ >> 8) * 3072 + (e_ & 255)); \
  } } while (0)

#define WRITEBUF(c_) do { \
  float* dst_ = th_base + ((c_) & 1) * 8320; \
  _Pragma("unroll") \
  for (int i_ = 0; i_ < 8; ++i_) { \
    int e_ = i_ * 1024 + tid * 4; \
    *(float4*)(dst_ + (e_ >> 8) * 260 + (e_ & 255)) = pf[i_]; \
  } } while (0)

#define COMPUTE_CHUNK(c_) do { \
  const float* tb_ = th_base + ((c_) & 1) * 8320; \
  const float* t0_ = tb_ + bb * 260 + kb; \
  const float* t1_ = t0_ + 4160; \
  const float* w0_ = W_lds + jg * 1028 + (c_) * 256 + kb; \
  const float* w1_ = w0_ + 8224; \
  _Pragma("unroll") \
  for (int kk = 0; kk < 128; kk += 8) { \
    float4 wa0 = *(const float4*)(w0_ + kk); \
    float4 wa1 = *(const float4*)(w0_ + kk + 4); \
    float4 wb0 = *(const float4*)(w1_ + kk); \
    float4 wb1 = *(const float4*)(w1_ + kk + 4); \
    float4 t0a = *(const float4*)(t0_ + kk); \
    float4 t0b = *(const float4*)(t0_ + kk + 4); \
    float4 t1a = *(const float4*)(t1_ + kk); \
    float4 t1b = *(const float4*)(t1_ + kk + 4); \
    acc00 += wa0.x*t0a.x + wa0.y*t0a.y + wa0.z*t0a.z + wa0.w*t0a.w \
           + wa1.x*t0b.x + wa1.y*t0b.y + wa1.z*t0b.z + wa1.w*t0b.w; \
    acc01 += wa0.x*t1a.x + wa0.y*t1a.y + wa0.z*t1a.z + wa0.w*t1a.w \
           + wa1.x*t1b.x + wa1.y*t1b.y + wa1.z*t1b.z + wa1.w*t1b.w; \
    acc10 += wb0.x*t0a.x + wb0.y*t0a.y + wb0.z*t0a.z + wb0.w*t0a.w \
           + wb1.x*t0b.x + wb1.y*t0b.y + wb1.z*t0b.z + wb1.w*t0b.w; \
    acc11 += wb0.x*t1a.x + wb0.y*t1a.y + wb0.z*t1a.z + wb0.w*t1a.w \
           + wb1.x*t1b.x + wb1.y*t1b.y + wb1.z*t1b.z + wb1.w*t1b.w; \
  } } while (0)

__global__ void __launch_bounds__(256, 1) rnn_main(
    const float* __restrict__ Wih,
    const float* __restrict__ W11,
    const float* __restrict__ W22,
    const float* __restrict__ W33,
    const float* __restrict__ W12,
    const float* __restrict__ W23,
    const float* __restrict__ Who,
    const float* __restrict__ Whc2,
    const float* __restrict__ Wr1,
    const float* __restrict__ Wr2,
    const float* __restrict__ Wr3,
    const int* __restrict__ id12_1, const int* __restrict__ id12_2,
    const int* __restrict__ id23_2, const int* __restrict__ id23_3,
    const float* __restrict__ ctx,
    const float* __restrict__ h0,
    float* __restrict__ ws,
    float* __restrict__ out) {

  extern __shared__ float smem[];
  float* W_lds   = smem + L_W;
  float* th_base = smem + L_TH;
  float* coupf   = smem + L_COUP;
  float* Wih_lds = smem + L_WIH;
  float* Hbuf    = smem + L_HBUF;
  float* redsc   = smem + L_RED;
  float* ci16    = smem + L_CI;
  int* gidx_lds  = (int*)(smem + L_GIDX);
  int* ql_j      = (int*)(smem + L_QLJ);
  int* ql_q      = (int*)(smem + L_QLQ);
  int* nq_sp     = (int*)(smem + L_NQ);

  const int g = blockIdx.x;
  const int tid = threadIdx.x;
  unsigned* flags = (unsigned*)(ws + BAR_OFF);
  unsigned* gen = flags + 4096;
  const int mmod = (g < 192) ? (g >> 6) : 0;
  const int loc0 = (g & 63) * 16;
  const int bb = tid & 15;
  const int jg = (tid >> 4) & 7;
  const int kh = tid >> 7;
  const int kb = kh * 128;
  float h00 = 0.f, h01 = 0.f, h10 = 0.f, h11 = 0.f;

  if (g < 192) {
    const float* Wsrc = (mmod == 0) ? W11 : ((mmod == 1) ? W22 : W33);
    // stage W slice (16 x 1024 fp32) into LDS once
    #pragma unroll
    for (int i = 0; i < 16; ++i) {
      float4 v = *(const float4*)&Wsrc[(size_t)(loc0 + i) * 1024 + tid * 4];
      *(float4*)&W_lds[i * 1028 + tid * 4] = v;
    }
    if (mmod == 0) {
      Wih_lds[tid] = Wih[(loc0 + (tid >> 4)) * 16 + (tid & 15)];
    }
    if (mmod == 1 && tid < 16) {
      ci16[tid] = ctx[0] * Whc2[(loc0 + tid) * 2];
    }
    if (mmod != 0 && tid < 205) {
      const int* gsrc = (mmod == 1) ? id12_1 : id23_2;
      gidx_lds[tid] = gsrc[tid];
    }
    if (tid == 0) {
      int cnt = 0;
      if (mmod != 0) {
        const int* scat = (mmod == 1) ? id12_2 : id23_3;
        for (int q = 0; q < 205; ++q) {
          int jj = scat[q] - loc0;
          if (jj >= 0 && jj < 16) { ql_j[cnt] = jj; ql_q[cnt] = q; ++cnt; }
        }
      }
      *nq_sp = cnt;
    }
    if (!kh) {
      int gn0 = mmod * 1024 + loc0 + jg;
      h00 = h0[bb * 3072 + gn0];
      h01 = h0[(bb + 16) * 3072 + gn0];
      h10 = h0[bb * 3072 + gn0 + 8];
      h11 = h0[(bb + 16) * 3072 + gn0 + 8];
    }
  }
  __syncthreads();

  #pragma unroll 1
  for (int t = 0; t < 512; ++t) {
    const int p = t & 1;
    const float* thbuf_p = ws + THBUF_OFF + (size_t)p * 98304;
    float*       thbuf_n = ws + THBUF_OFF + (size_t)(p ^ 1) * 98304;
    const float* thT_p   = ws + THT_OFF + (size_t)p * 98304;
    float*       thT_n   = ws + THT_OFF + (size_t)(p ^ 1) * 98304;

    if (g < 192) {
      const float* thmod = thbuf_p + mmod * 1024;
      // sparse gather staging lives in the SECOND half of th_base (chunk-1
      // region, 8320 floats >= 205*32=6560); WRITEBUF(0) uses the first half,
      // WRITEBUF(1) only runs after the c=0 top sync, by which time all
      // sparse reads are done.
      float* thsp = th_base + 8320;
      float4 pf[8];
      // zero coupling staging + prefetch chunk 0
      *(float4*)&coupf[tid * 4] = make_float4(0.f, 0.f, 0.f, 0.f);
      LOADPF(0);
      // ---- sparse coupling: coalesced gather into LDS ----
      if (mmod != 0) {
        const int rbase = (mmod == 1) ? 0 : 1024;
        for (int e = tid; e < 1640; e += 256) {
          int pp = e >> 3, bq = (e & 7) * 4;
          float4 v = ldc_f4(&thT_p[(size_t)(rbase + gidx_lds[pp]) * 32 + bq]);
          *(float4*)&thsp[pp * 32 + bq] = v;
        }
      }
      __syncthreads();
      // ---- sparse coupling: dot products from LDS ----
      if (mmod != 0) {
        const int ntask = *nq_sp * 64;
        const float* Wsp = (mmod == 1) ? W12 : W23;
        for (int task = tid; task < ntask; task += 256) {
          int kh2 = task & 1;
          int b = (task >> 1) & 31;
          int qi = task >> 6;
          int q = ql_q[qi], jj = ql_j[qi];
          int p0 = kh2 ? 103 : 0;
          int p1 = kh2 ? 205 : 103;
          float v = 0.0f;
          for (int pp = p0; pp < p1; ++pp) {
            v += Wsp[q * 205 + pp] * thsp[pp * 32 + b];
          }
          coupf[kh2 * 512 + jj * 32 + b] = v;
        }
      }
      WRITEBUF(0);
      // ---- main GEMM: W from LDS, th double-buffered ----
      float acc00 = 0.f, acc01 = 0.f, acc10 = 0.f, acc11 = 0.f;
      #pragma unroll 1
      for (int c = 0; c < 4; ++c) {
        __syncthreads();
        if (c < 3) LOADPF(c + 1);
        COMPUTE_CHUNK(c);
        if (c < 3) WRITEBUF(c + 1);
      }
      __syncthreads();
      if (kh) {
        int l = (tid - 128) * 4;
        redsc[l] = acc00; redsc[l + 1] = acc01;
        redsc[l + 2] = acc10; redsc[l + 3] = acc11;
      }
      __syncthreads();
      if (!kh) {
        acc00 += redsc[tid * 4];     acc01 += redsc[tid * 4 + 1];
        acc10 += redsc[tid * 4 + 2]; acc11 += redsc[tid * 4 + 3];
        const float* xTt = ws + XT_OFF + t * 512;
        const float* wnt = ws + WN_OFF + t * 3072;
        float accs[4] = {acc00, acc01, acc10, acc11};
        float hs[4] = {h00, h01, h10, h11};
        #pragma unroll
        for (int js = 0; js < 2; ++js) {
          int j = jg + js * 8;
          int gn = mmod * 1024 + loc0 + j;
          #pragma unroll
          for (int bs = 0; bs < 2; ++bs) {
            int b = bb + bs * 16;
            float dot = accs[js * 2 + bs];
            float extra;
            if (mmod == 0) {
              extra = 0.f;
              #pragma unroll
              for (int ii = 0; ii < 16; ++ii)
                extra += xTt[b * 16 + ii] * Wih_lds[j * 16 + ii];
            } else {
              float cp = coupf[j * 32 + b] + coupf[512 + j * 32 + b];
              extra = (mmod == 1) ? cp * ci16[j] : cp;
            }
            float hv = hs[js * 2 + bs];
            hv = hv + (dot + extra + wnt[gn] - hv) / 10.0f;
            hs[js * 2 + bs] = hv;
            float tv = tanhf(hv);
            stc_f1(&thbuf_n[b * 3072 + gn], tv);
            stc_f1(&thT_n[gn * 32 + b], tv);
            Hbuf[(j * 32 + b) * 4 + (t & 3)] = tv;
          }
        }
        h00 = hs[0]; h01 = hs[1]; h10 = hs[2]; h11 = hs[3];
      }
      if ((t & 3) == 3) {
        __syncthreads();
        #pragma unroll
        for (int r = 0; r < 2; ++r) {
          int o = tid * 2 + r;
          int j = o >> 5, b = o & 31;
          size_t gn = (size_t)(mmod * 1024 + loc0 + j);
          float4 v = *(const float4*)&Hbuf[o * 4];
          nt_store_f4(&out[((size_t)b * 3072 + gn) * 512 + (t - 3)], v);
        }
      }
    } else {
      // ---- aux WGs: y and yr readouts ----
      const int w = tid >> 6, lane = tid & 63;
      const int gw = (g - 192) * 4 + w;
      float* auxb = coupf;  // aux-only alias
      for (int s = 0; s < 4; ++s) {
        const int u = gw + s * 256;
        if (u >= 800) break;
        float a0 = 0.f, a1 = 0.f, a2 = 0.f, a3 = 0.f;
        if (u < 768) {
          const int mm = u >> 8;
          const int rem = u & 255;
          const int b = rem >> 3;
          const int rr0 = (rem & 7) * 4;
          const float* Wr = (mm == 0) ? Wr1 : ((mm == 1) ? Wr2 : Wr3);
          const float* trow = thbuf_p + b * 3072 + mm * 1024;
          #pragma unroll
          for (int it = 0; it < 4; ++it) {
            int k = it * 256 + lane * 4;
            float4 tv = ldc_f4(trow + k);
            float4 q0 = *(const float4*)&Wr[(rr0 + 0) * 1024 + k];
            float4 q1 = *(const float4*)&Wr[(rr0 + 1) * 1024 + k];
            float4 q2 = *(const float4*)&Wr[(rr0 + 2) * 1024 + k];
            float4 q3 = *(const float4*)&Wr[(rr0 + 3) * 1024 + k];
            a0 += tv.x*q0.x + tv.y*q0.y + tv.z*q0.z + tv.w*q0.w;
            a1 += tv.x*q1.x + tv.y*q1.y + tv.z*q1.z + tv.w*q1.w;
            a2 += tv.x*q2.x + tv.y*q2.y + tv.z*q2.z + tv.w*q2.w;
            a3 += tv.x*q3.x + tv.y*q3.y + tv.z*q3.z + tv.w*q3.w;
          }
        } else {
          const int b = u - 768;
          const float* trow = thbuf_p + b * 3072 + 2048;
          #pragma unroll
          for (int it = 0; it < 4; ++it) {
            int k = it * 256 + lane * 4;
            float4 tv = ldc_f4(trow + k);
            float4 q0 = *(const float4*)&Who[k];
            a0 += tv.x*q0.x + tv.y*q0.y + tv.z*q0.z + tv.w*q0.w;
          }
        }
        #pragma unroll
        for (int off = 32; off > 0; off >>= 1) {
          a0 += __shfl_xor(a0, off);
          a1 += __shfl_xor(a1, off);
          a2 += __shfl_xor(a2, off);
          a3 += __shfl_xor(a3, off);
        }
        if (lane == 0) {
          int base = ((w * 4 + s) * 4) * 4 + (t & 3);
          auxb[base] = tanhf(a0);
          if (u < 768) {
            auxb[base + 4]  = tanhf(a1);
            auxb[base + 8]  = tanhf(a2);
            auxb[base + 12] = tanhf(a3);
          }
        }
      }
      if ((t & 3) == 3) {
        __syncthreads();
        int s = lane >> 2, rv = lane & 3;
        if (lane < 16) {
          int u = gw + s * 256;
          if (u < 768) {
            int mm = u >> 8, rem = u & 255, b = rem >> 3, rr = (rem & 7) * 4 + rv;
            float4 v = *(const float4*)&auxb[((w * 4 + s) * 4 + rv) * 4];
            nt_store_f4(&out[(size_t)YR0_OFF + ((size_t)(b * 32 + rr) * 3 + mm) * 512 + (t - 3)], v);
          } else if (u < 800 && rv == 0) {
            float4 v = *(const float4*)&auxb[((w * 4 + s) * 4) * 4];
            nt_store_f4(&out[(size_t)Y0_OFF + (size_t)(u - 768) * 512 + (t - 3)], v);
          }
        }
      }
    }
    flagBarrier(flags, gen, g, tid, (unsigned)(t + 1));
  }
}

extern "C" void kernel_launch(void* const* d_in, const int* in_sizes, int n_in,
                              void* d_out, int out_size, void* d_ws, size_t ws_size,
                              hipStream_t stream) {
  (void)in_sizes; (void)n_in; (void)out_size; (void)ws_size;
  const float* x    = (const float*)d_in[0];
  const float* h0   = (const float*)d_in[1];
  const float* ctx  = (const float*)d_in[2];
  const float* iWN  = (const float*)d_in[3];
  const float* Wih  = (const float*)d_in[4];
  const float* W11  = (const float*)d_in[5];
  const float* W22  = (const float*)d_in[6];
  const float* W33  = (const float*)d_in[7];
  const float* W12  = (const float*)d_in[8];
  const float* W23  = (const float*)d_in[9];
  const float* Who  = (const float*)d_in[10];
  const float* Whc2 = (const float*)d_in[11];
  const float* Wr1  = (const float*)d_in[12];
  const float* Wr2  = (const float*)d_in[13];
  const float* Wr3  = (const float*)d_in[14];
  const int* id12_1 = (const int*)d_in[15];
  const int* id12_2 = (const int*)d_in[16];
  const int* id23_2 = (const int*)d_in[17];
  const int* id23_3 = (const int*)d_in[18];
  float* ws = (float*)d_ws;
  float* out = (float*)d_out;

  hipFuncSetAttribute(reinterpret_cast<const void*>(rnn_main),
                      hipFuncAttributeMaxDynamicSharedMemorySize, SMEM_BYTES);
  hipLaunchKernelGGL(prep1, dim3(512), dim3(256), 0, stream, x, h0, ws);
  hipLaunchKernelGGL(prep2, dim3(12), dim3(256), 0, stream, iWN, ws);
  hipLaunchKernelGGL(rnn_main, dim3(256), dim3(256), SMEM_BYTES, stream,
                     Wih, W11, W22, W33, W12, W23, Who, Whc2, Wr1, Wr2, Wr3,
                     id12_1, id12_2, id23_2, id23_3, ctx, h0, ws, out);
}

// Round 5
// 16586.151 us; speedup vs baseline: 3.0729x; 1.7301x over previous
//
#include <hip/hip_runtime.h>
#include <math.h>

// ---- workspace layout (float units) ----
#define WN_OFF    0          // 512*3072 filtered noise, [t][n]
#define THBUF_OFF 1572864    // 2 * 32*3072 fp32 tanh(h), [parity][b][n]
#define THT_OFF   1769472    // 2 * 3072*32 fp32 tanh(h) transposed, [parity][n][b]
#define XT_OFF    1966080    // 512*512 fp32 x transposed, [t][b*16+i]
#define BAR_OFF   2228224    // flags: 256*16 uints + gen: 32*16 uints at [4096..4607]
// ---- output layout (float units) ----
#define Y0_OFF    50331648
#define YR0_OFF   50348032
#define MASTER    255

// ---- dynamic LDS layout (float units) ----
#define L_W      0            // 16*1028 = 16448 (aux WGs reuse as per-wave staging)
#define L_TH     16448        // 2*32*260 = 16640 (2nd half doubles as sparse gather buf)
#define L_COUP   33088        // 1024 (aux WGs alias this as auxb)
#define L_WIH    34112        // 256
#define L_HBUF   34368        // 2048
#define L_RED    36416        // 1024 (lower 512: K-reduction; upper 512: thcur staging)
#define L_CI     37440        // 16
#define L_GIDX   37456        // 208 ints
#define L_QLJ    37664        // 16 ints
#define L_QLQ    37680        // 16 ints
#define L_NQ     37696        // 1 int
#define SMEM_FLOATS 37760
#define SMEM_BYTES  (SMEM_FLOATS * 4)

typedef float fx4 __attribute__((ext_vector_type(4)));

__device__ __forceinline__ void nt_store_f4(float* p, float4 v) {
  fx4 w; w.x = v.x; w.y = v.y; w.z = v.z; w.w = v.w;
  __builtin_nontemporal_store(w, (fx4*)p);
}

// 16B write-through (sc0 sc1) store to the device-coherent point. Inputs are
// complete values -> no asm-output spill hazard. Visibility enforced by the
// explicit vmcnt(0) drain in flagBarrier.
__device__ __forceinline__ void stc_f4(float* p, float4 v) {
  fx4 w; w.x = v.x; w.y = v.y; w.z = v.z; w.w = v.w;
  asm volatile("global_store_dwordx4 %0, %1, off sc0 sc1" :: "v"(p), "v"(w) : "memory");
}

// Compiler-tracked 16B global->LDS direct load, coherent (sc0|sc1 = aux 17).
// No VGPR destination -> no spill hazard; vmcnt handled by compiler (drained
// before every s_barrier). LDS base must be wave-uniform; global addr per-lane.
#define GLOAD_LDS16(gp_, lp_)                                                  \
  __builtin_amdgcn_global_load_lds(                                            \
      (__attribute__((address_space(1))) void*)(void*)(gp_),                   \
      (__attribute__((address_space(3))) void*)(lp_), 16, 0, 17)

__global__ void prep1(const float* __restrict__ x,
                      const float* __restrict__ h0,
                      float* __restrict__ ws) {
  int i = blockIdx.x * blockDim.x + threadIdx.x;
  const int stride = gridDim.x * blockDim.x;
  const int NXT = 512 * 512;
  const int NTH0 = 32 * 3072;
  const int NBAR = 4608;
  for (; i < NXT + NTH0 + NBAR; i += stride) {
    if (i < NXT) {
      int t = i >> 9, bi = i & 511;
      ws[XT_OFF + i] = x[bi * 512 + t];
    } else if (i < NXT + NTH0) {
      int e = i - NXT;
      int b = e / 3072, n = e - b * 3072;
      float v = tanhf(h0[e]);
      ws[THBUF_OFF + e] = v;
      ws[THT_OFF + n * 32 + b] = v;
    } else {
      ((unsigned*)(ws + BAR_OFF))[i - (NXT + NTH0)] = 0u;
    }
  }
}

__global__ void prep2(const float* __restrict__ iwn,
                      float* __restrict__ ws) {
  int n = blockIdx.x * blockDim.x + threadIdx.x;
  if (n >= 3072) return;
  const float s10 = sqrtf(10.0f);
  const float a = expf(-0.1f);
  float prev = s10 * iwn[n * 512];
  ws[WN_OFF + n] = 0.01f * prev;
  for (int t = 1; t < 512; ++t) {
    float cur = s10 * iwn[n * 512 + t];
    prev = cur + (prev - cur) * a;
    ws[WN_OFF + t * 3072 + n] = 0.01f * prev;
  }
}

// Fence-free flag barrier. Gen broadcast to 32 spaced lines; WG g polls line
// g>>3. Leading vmcnt(0) drains the asm publish stores before the flag store.
__device__ __forceinline__ void flagBarrier(unsigned* flags, unsigned* gen,
                                            int g, int tid, unsigned tv) {
  asm volatile("s_waitcnt vmcnt(0)" ::: "memory");
  __syncthreads();
  if (tid == 0)
    __hip_atomic_store(&flags[g * 16], tv, __ATOMIC_RELAXED, __HIP_MEMORY_SCOPE_AGENT);
  if (g == MASTER) {
    while (__hip_atomic_load(&flags[tid * 16], __ATOMIC_RELAXED,
                             __HIP_MEMORY_SCOPE_AGENT) < tv)
      __builtin_amdgcn_s_sleep(1);
    __syncthreads();
    if (tid < 32)
      __hip_atomic_store(&gen[tid * 16], tv, __ATOMIC_RELAXED, __HIP_MEMORY_SCOPE_AGENT);
  } else {
    if (tid == 0) {
      while (__hip_atomic_load(&gen[(g >> 3) * 16], __ATOMIC_RELAXED,
                               __HIP_MEMORY_SCOPE_AGENT) < tv)
        __builtin_amdgcn_s_sleep(1);
    }
    __syncthreads();
  }
}

// Stage one 32x256 th chunk into LDS half ((c)&1): 8 wave-level 16B LDS-direct
// loads. Row = i*4 + wave; lane covers 16B of the 1KB row. Dest rows at stride
// 260 floats (pad never written by the load — each call is one full row).
#define LOADPF_LDS(c_) do {                                                    \
  const float* src_ = thmod + (c_) * 256;                                      \
  float* dsth_ = th_base + (((c_) & 1) ? 8320 : 0);                            \
  _Pragma("unroll")                                                            \
  for (int i_ = 0; i_ < 8; ++i_) {                                             \
    int row_ = i_ * 4 + wv;                                                    \
    GLOAD_LDS16(src_ + (size_t)row_ * 3072 + lane16, dsth_ + row_ * 260);      \
  } } while (0)

#define COMPUTE_CHUNK(c_) do { \
  const float* tb_ = th_base + ((c_) & 1) * 8320; \
  const float* t0_ = tb_ + bb * 260 + kb; \
  const float* t1_ = t0_ + 4160; \
  const float* w0_ = W_lds + jg * 1028 + (c_) * 256 + kb; \
  const float* w1_ = w0_ + 8224; \
  _Pragma("unroll") \
  for (int kk = 0; kk < 128; kk += 8) { \
    float4 wa0 = *(const float4*)(w0_ + kk); \
    float4 wa1 = *(const float4*)(w0_ + kk + 4); \
    float4 wb0 = *(const float4*)(w1_ + kk); \
    float4 wb1 = *(const float4*)(w1_ + kk + 4); \
    float4 t0a = *(const float4*)(t0_ + kk); \
    float4 t0b = *(const float4*)(t0_ + kk + 4); \
    float4 t1a = *(const float4*)(t1_ + kk); \
    float4 t1b = *(const float4*)(t1_ + kk + 4); \
    acc00 += wa0.x*t0a.x + wa0.y*t0a.y + wa0.z*t0a.z + wa0.w*t0a.w \
           + wa1.x*t0b.x + wa1.y*t0b.y + wa1.z*t0b.z + wa1.w*t0b.w; \
    acc01 += wa0.x*t1a.x + wa0.y*t1a.y + wa0.z*t1a.z + wa0.w*t1a.w \
           + wa1.x*t1b.x + wa1.y*t1b.y + wa1.z*t1b.z + wa1.w*t1b.w; \
    acc10 += wb0.x*t0a.x + wb0.y*t0a.y + wb0.z*t0a.z + wb0.w*t0a.w \
           + wb1.x*t0b.x + wb1.y*t0b.y + wb1.z*t0b.z + wb1.w*t0b.w; \
    acc11 += wb0.x*t1a.x + wb0.y*t1a.y + wb0.z*t1a.z + wb0.w*t1a.w \
           + wb1.x*t1b.x + wb1.y*t1b.y + wb1.z*t1b.z + wb1.w*t1b.w; \
  } } while (0)

__global__ void __launch_bounds__(256, 1) rnn_main(
    const float* __restrict__ Wih,
    const float* __restrict__ W11,
    const float* __restrict__ W22,
    const float* __restrict__ W33,
    const float* __restrict__ W12,
    const float* __restrict__ W23,
    const float* __restrict__ Who,
    const float* __restrict__ Whc2,
    const float* __restrict__ Wr1,
    const float* __restrict__ Wr2,
    const float* __restrict__ Wr3,
    const int* __restrict__ id12_1, const int* __restrict__ id12_2,
    const int* __restrict__ id23_2, const int* __restrict__ id23_3,
    const float* __restrict__ ctx,
    const float* __restrict__ h0,
    float* __restrict__ ws,
    float* __restrict__ out) {

  extern __shared__ float smem[];
  float* W_lds   = smem + L_W;
  float* th_base = smem + L_TH;
  float* coupf   = smem + L_COUP;
  float* Wih_lds = smem + L_WIH;
  float* Hbuf    = smem + L_HBUF;
  float* redsc   = smem + L_RED;
  float* thcur   = smem + L_RED + 512;
  float* ci16    = smem + L_CI;
  int* gidx_lds  = (int*)(smem + L_GIDX);
  int* ql_j      = (int*)(smem + L_QLJ);
  int* ql_q      = (int*)(smem + L_QLQ);
  int* nq_sp     = (int*)(smem + L_NQ);

  const int g = blockIdx.x;
  const int tid = threadIdx.x;
  unsigned* flags = (unsigned*)(ws + BAR_OFF);
  unsigned* gen = flags + 4096;
  const int mmod = (g < 192) ? (g >> 6) : 0;
  const int loc0 = (g & 63) * 16;
  const int bb = tid & 15;
  const int jg = (tid >> 4) & 7;
  const int kh = tid >> 7;
  const int kb = kh * 128;
  const int wv = tid >> 6;           // wave id
  const int lane16 = (tid & 63) * 4; // 16B lane offset (floats)
  float h00 = 0.f, h01 = 0.f, h10 = 0.f, h11 = 0.f;

  if (g < 192) {
    const float* Wsrc = (mmod == 0) ? W11 : ((mmod == 1) ? W22 : W33);
    // stage W slice (16 x 1024 fp32) into LDS once
    #pragma unroll
    for (int i = 0; i < 16; ++i) {
      float4 v = *(const float4*)&Wsrc[(size_t)(loc0 + i) * 1024 + tid * 4];
      *(float4*)&W_lds[i * 1028 + tid * 4] = v;
    }
    if (mmod == 0) {
      Wih_lds[tid] = Wih[(loc0 + (tid >> 4)) * 16 + (tid & 15)];
    }
    if (mmod == 1 && tid < 16) {
      ci16[tid] = ctx[0] * Whc2[(loc0 + tid) * 2];
    }
    if (mmod != 0 && tid < 205) {
      const int* gsrc = (mmod == 1) ? id12_1 : id23_2;
      gidx_lds[tid] = gsrc[tid];
    }
    if (tid == 0) {
      int cnt = 0;
      if (mmod != 0) {
        const int* scat = (mmod == 1) ? id12_2 : id23_3;
        for (int q = 0; q < 205; ++q) {
          int jj = scat[q] - loc0;
          if (jj >= 0 && jj < 16) { ql_j[cnt] = jj; ql_q[cnt] = q; ++cnt; }
        }
      }
      *nq_sp = cnt;
    }
    if (!kh) {
      int gn0 = mmod * 1024 + loc0 + jg;
      h00 = h0[bb * 3072 + gn0];
      h01 = h0[(bb + 16) * 3072 + gn0];
      h10 = h0[bb * 3072 + gn0 + 8];
      h11 = h0[(bb + 16) * 3072 + gn0 + 8];
    }
  }
  __syncthreads();

  #pragma unroll 1
  for (int t = 0; t < 512; ++t) {
    const int p = t & 1;
    const float* thbuf_p = ws + THBUF_OFF + (size_t)p * 98304;
    float*       thbuf_n = ws + THBUF_OFF + (size_t)(p ^ 1) * 98304;
    const float* thT_p   = ws + THT_OFF + (size_t)p * 98304;
    float*       thT_n   = ws + THT_OFF + (size_t)(p ^ 1) * 98304;

    if (g < 192) {
      const float* thmod = thbuf_p + mmod * 1024;
      float* thsp = th_base + 8320;  // sparse gather buf (half1 of th_base)
      // zero coupling staging
      *(float4*)&coupf[tid * 4] = make_float4(0.f, 0.f, 0.f, 0.f);
      // ---- sparse gather: 7 coherent 16B LDS-direct loads/thread ----
      // e = tid + i*256 covers 0..1639 exactly once; clamped lanes (e>1639)
      // duplicate-load a valid row and land beyond thsp's used 6560 floats
      // (max float offset 4*1791+3 = 7167 < 8320) — harmless.
      if (mmod != 0) {
        const int rbase = (mmod == 1) ? 0 : 1024;
        #pragma unroll
        for (int i = 0; i < 7; ++i) {
          int e = tid + i * 256;
          if (e > 1639) e = 1639;
          int pp = e >> 3, bq = (e & 7) * 4;
          GLOAD_LDS16(&thT_p[(size_t)(rbase + gidx_lds[pp]) * 32 + bq],
                      thsp + 4 * (i * 256 + wv * 64));
        }
      }
      // ---- prefetch GEMM chunk 0 into half0 ----
      LOADPF_LDS(0);
      __syncthreads();   // compiler drains vmcnt before barrier: thsp + half0 ready
      // ---- sparse coupling: dot products from LDS ----
      if (mmod != 0) {
        const int ntask = *nq_sp * 64;
        const float* Wsp = (mmod == 1) ? W12 : W23;
        for (int task = tid; task < ntask; task += 256) {
          int kh2 = task & 1;
          int b = (task >> 1) & 31;
          int qi = task >> 6;
          int q = ql_q[qi], jj = ql_j[qi];
          int p0 = kh2 ? 103 : 0;
          int p1 = kh2 ? 205 : 103;
          float v = 0.0f;
          for (int pp = p0; pp < p1; ++pp) {
            v += Wsp[q * 205 + pp] * thsp[pp * 32 + b];
          }
          coupf[kh2 * 512 + jj * 32 + b] = v;
        }
      }
      __syncthreads();   // thsp free (chunk1 will overwrite half1)
      // ---- main GEMM: W from LDS, th double-buffered via LDS-direct loads ----
      float acc00 = 0.f, acc01 = 0.f, acc10 = 0.f, acc11 = 0.f;
      #pragma unroll 1
      for (int c = 0; c < 4; ++c) {
        if (c < 3) LOADPF_LDS(c + 1);   // into the half freed at last barrier
        COMPUTE_CHUNK(c);
        __syncthreads();                // chunk c+1 landed; half c&1 freed
      }
      if (kh) {
        int l = (tid - 128) * 4;
        redsc[l] = acc00; redsc[l + 1] = acc01;
        redsc[l + 2] = acc10; redsc[l + 3] = acc11;
      }
      __syncthreads();
      if (!kh) {
        acc00 += redsc[tid * 4];     acc01 += redsc[tid * 4 + 1];
        acc10 += redsc[tid * 4 + 2]; acc11 += redsc[tid * 4 + 3];
        const float* xTt = ws + XT_OFF + t * 512;
        const float* wnt = ws + WN_OFF + t * 3072;
        float accs[4] = {acc00, acc01, acc10, acc11};
        float hs[4] = {h00, h01, h10, h11};
        #pragma unroll
        for (int js = 0; js < 2; ++js) {
          int j = jg + js * 8;
          int gn = mmod * 1024 + loc0 + j;
          #pragma unroll
          for (int bs = 0; bs < 2; ++bs) {
            int b = bb + bs * 16;
            float dot = accs[js * 2 + bs];
            float extra;
            if (mmod == 0) {
              extra = 0.f;
              #pragma unroll
              for (int ii = 0; ii < 16; ++ii)
                extra += xTt[b * 16 + ii] * Wih_lds[j * 16 + ii];
            } else {
              float cp = coupf[j * 32 + b] + coupf[512 + j * 32 + b];
              extra = (mmod == 1) ? cp * ci16[j] : cp;
            }
            float hv = hs[js * 2 + bs];
            hv = hv + (dot + extra + wnt[gn] - hv) / 10.0f;
            hs[js * 2 + bs] = hv;
            float tv = tanhf(hv);
            thcur[j * 32 + b] = tv;               // LDS staging for wide stores
            Hbuf[(j * 32 + b) * 4 + (t & 3)] = tv;
          }
        }
        h00 = hs[0]; h01 = hs[1]; h10 = hs[2]; h11 = hs[3];
      }
      __syncthreads();
      // ---- publish th with ONE 16B write-through store per thread ----
      {
        const int base = mmod * 1024 + loc0;
        if (tid < 128) {
          int b = tid & 31, q = tid >> 5;
          float4 v;
          v.x = thcur[(4 * q + 0) * 32 + b];
          v.y = thcur[(4 * q + 1) * 32 + b];
          v.z = thcur[(4 * q + 2) * 32 + b];
          v.w = thcur[(4 * q + 3) * 32 + b];
          stc_f4(&thbuf_n[(size_t)b * 3072 + base + 4 * q], v);
        } else {
          int u = tid - 128;
          int j = u >> 3, vq = u & 7;
          float4 v = *(const float4*)&thcur[j * 32 + 4 * vq];
          stc_f4(&thT_n[(size_t)(base + j) * 32 + 4 * vq], v);
        }
      }
      if ((t & 3) == 3) {
        __syncthreads();
        #pragma unroll
        for (int r = 0; r < 2; ++r) {
          int o = tid * 2 + r;
          int j = o >> 5, b = o & 31;
          size_t gn = (size_t)(mmod * 1024 + loc0 + j);
          float4 v = *(const float4*)&Hbuf[o * 4];
          nt_store_f4(&out[((size_t)b * 3072 + gn) * 512 + (t - 3)], v);
        }
      }
    } else {
      // ---- aux WGs: y and yr readouts ----
      const int w = tid >> 6, lane = tid & 63;
      const int gw = (g - 192) * 4 + w;
      float* auxb = coupf;            // aux-only alias
      float* stg = W_lds + w * 1024;  // per-wave 4x256 staging (W_lds unused here)
      for (int s = 0; s < 4; ++s) {
        const int u = gw + s * 256;
        if (u >= 800) break;
        float a0 = 0.f, a1 = 0.f, a2 = 0.f, a3 = 0.f;
        if (u < 768) {
          const int mm = u >> 8;
          const int rem = u & 255;
          const int b = rem >> 3;
          const int rr0 = (rem & 7) * 4;
          const float* Wr = (mm == 0) ? Wr1 : ((mm == 1) ? Wr2 : Wr3);
          const float* trow = thbuf_p + b * 3072 + mm * 1024;
          #pragma unroll
          for (int it = 0; it < 4; ++it)
            GLOAD_LDS16(trow + it * 256 + lane * 4, stg + it * 256);
          asm volatile("s_waitcnt vmcnt(0)" ::: "memory");
          __builtin_amdgcn_sched_barrier(0);
          #pragma unroll
          for (int it = 0; it < 4; ++it) {
            int k = it * 256 + lane * 4;
            float4 tv = *(const float4*)&stg[it * 256 + lane * 4];
            float4 q0 = *(const float4*)&Wr[(rr0 + 0) * 1024 + k];
            float4 q1 = *(const float4*)&Wr[(rr0 + 1) * 1024 + k];
            float4 q2 = *(const float4*)&Wr[(rr0 + 2) * 1024 + k];
            float4 q3 = *(const float4*)&Wr[(rr0 + 3) * 1024 + k];
            a0 += tv.x*q0.x + tv.y*q0.y + tv.z*q0.z + tv.w*q0.w;
            a1 += tv.x*q1.x + tv.y*q1.y + tv.z*q1.z + tv.w*q1.w;
            a2 += tv.x*q2.x + tv.y*q2.y + tv.z*q2.z + tv.w*q2.w;
            a3 += tv.x*q3.x + tv.y*q3.y + tv.z*q3.z + tv.w*q3.w;
          }
          __builtin_amdgcn_sched_barrier(0);
        } else {
          const int b = u - 768;
          const float* trow = thbuf_p + b * 3072 + 2048;
          #pragma unroll
          for (int it = 0; it < 4; ++it)
            GLOAD_LDS16(trow + it * 256 + lane * 4, stg + it * 256);
          asm volatile("s_waitcnt vmcnt(0)" ::: "memory");
          __builtin_amdgcn_sched_barrier(0);
          #pragma unroll
          for (int it = 0; it < 4; ++it) {
            int k = it * 256 + lane * 4;
            float4 tv = *(const float4*)&stg[it * 256 + lane * 4];
            float4 q0 = *(const float4*)&Who[k];
            a0 += tv.x*q0.x + tv.y*q0.y + tv.z*q0.z + tv.w*q0.w;
          }
          __builtin_amdgcn_sched_barrier(0);
        }
        #pragma unroll
        for (int off = 32; off > 0; off >>= 1) {
          a0 += __shfl_xor(a0, off);
          a1 += __shfl_xor(a1, off);
          a2 += __shfl_xor(a2, off);
          a3 += __shfl_xor(a3, off);
        }
        if (lane == 0) {
          int base = ((w * 4 + s) * 4) * 4 + (t & 3);
          auxb[base] = tanhf(a0);
          if (u < 768) {
            auxb[base + 4]  = tanhf(a1);
            auxb[base + 8]  = tanhf(a2);
            auxb[base + 12] = tanhf(a3);
          }
        }
      }
      if ((t & 3) == 3) {
        __syncthreads();
        int s = lane >> 2, rv = lane & 3;
        if (lane < 16) {
          int u = gw + s * 256;
          if (u < 768) {
            int mm = u >> 8, rem = u & 255, b = rem >> 3, rr = (rem & 7) * 4 + rv;
            float4 v = *(const float4*)&auxb[((w * 4 + s) * 4 + rv) * 4];
            nt_store_f4(&out[(size_t)YR0_OFF + ((size_t)(b * 32 + rr) * 3 + mm) * 512 + (t - 3)], v);
          } else if (u < 800 && rv == 0) {
            float4 v = *(const float4*)&auxb[((w * 4 + s) * 4) * 4];
            nt_store_f4(&out[(size_t)Y0_OFF + (size_t)(u - 768) * 512 + (t - 3)], v);
          }
        }
      }
    }
    flagBarrier(flags, gen, g, tid, (unsigned)(t + 1));
  }
}

extern "C" void kernel_launch(void* const* d_in, const int* in_sizes, int n_in,
                              void* d_out, int out_size, void* d_ws, size_t ws_size,
                              hipStream_t stream) {
  (void)in_sizes; (void)n_in; (void)out_size; (void)ws_size;
  const float* x    = (const float*)d_in[0];
  const float* h0   = (const float*)d_in[1];
  const float* ctx  = (const float*)d_in[2];
  const float* iWN  = (const float*)d_in[3];
  const float* Wih  = (const float*)d_in[4];
  const float* W11  = (const float*)d_in[5];
  const float* W22  = (const float*)d_in[6];
  const float* W33  = (const float*)d_in[7];
  const float* W12  = (const float*)d_in[8];
  const float* W23  = (const float*)d_in[9];
  const float* Who  = (const float*)d_in[10];
  const float* Whc2 = (const float*)d_in[11];
  const float* Wr1  = (const float*)d_in[12];
  const float* Wr2  = (const float*)d_in[13];
  const float* Wr3  = (const float*)d_in[14];
  const int* id12_1 = (const int*)d_in[15];
  const int* id12_2 = (const int*)d_in[16];
  const int* id23_2 = (const int*)d_in[17];
  const int* id23_3 = (const int*)d_in[18];
  float* ws = (float*)d_ws;
  float* out = (float*)d_out;

  hipFuncSetAttribute(reinterpret_cast<const void*>(rnn_main),
                      hipFuncAttributeMaxDynamicSharedMemorySize, SMEM_BYTES);
  hipLaunchKernelGGL(prep1, dim3(512), dim3(256), 0, stream, x, h0, ws);
  hipLaunchKernelGGL(prep2, dim3(12), dim3(256), 0, stream, iWN, ws);
  hipLaunchKernelGGL(rnn_main, dim3(256), dim3(256), SMEM_BYTES, stream,
                     Wih, W11, W22, W33, W12, W23, Who, Whc2, Wr1, Wr2, Wr3,
                     id12_1, id12_2, id23_2, id23_3, ctx, h0, ws, out);
}

// Round 6
// 12713.992 us; speedup vs baseline: 4.0088x; 1.3046x over previous
//
#include <hip/hip_runtime.h>
#include <math.h>

// ---- workspace layout (float units) ----
#define WN_OFF    0          // 512*3072 filtered noise, [t][n]
#define THBUF_OFF 1572864    // 2 * 32*3072 fp32 tanh(h), [parity][b][n]
#define THT_OFF   1769472    // 2 * 3072*32 fp32 tanh(h) transposed, [parity][n][b]
#define XT_OFF    1966080    // 512*512 fp32 x transposed, [t][b*16+i]
#define BAR_OFF   2228224    // flags: 256*16 uints + gen: 32*16 uints at [4096..4607]
// ---- output layout (float units) ----
#define Y0_OFF    50331648
#define YR0_OFF   50348032
#define MASTER    255

// ---- dynamic LDS layout (float units) ----
#define L_W      0            // 16*1028 = 16448 (aux WGs reuse as per-wave staging)
#define L_TH     16448        // 2*32*260 = 16640; half0 also hosts red2 (512*13)
#define L_COUP   33088        // 1024 (aux WGs alias this as auxb)
#define L_WIH    34112        // 256
#define L_HBUF   34368        // 2048
#define L_RED    36416        // 1024 (upper 512: thcur staging)
#define L_CI     37440        // 16
#define L_GIDX   37456        // 208 ints
#define L_QLJ    37664        // 16 ints
#define L_QLQ    37680        // 16 ints
#define L_NQ     37696        // 1 int
#define SMEM_FLOATS 37760
#define SMEM_BYTES  (SMEM_FLOATS * 4)

typedef float fx4 __attribute__((ext_vector_type(4)));

__device__ __forceinline__ void nt_store_f4(float* p, float4 v) {
  fx4 w; w.x = v.x; w.y = v.y; w.z = v.z; w.w = v.w;
  __builtin_nontemporal_store(w, (fx4*)p);
}

// 16B write-through (sc0 sc1) store to the device-coherent point.
__device__ __forceinline__ void stc_f4(float* p, float4 v) {
  fx4 w; w.x = v.x; w.y = v.y; w.z = v.z; w.w = v.w;
  asm volatile("global_store_dwordx4 %0, %1, off sc0 sc1" :: "v"(p), "v"(w) : "memory");
}

// Compiler-tracked 16B global->LDS direct load, coherent (sc0|sc1 = aux 17).
#define GLOAD_LDS16(gp_, lp_)                                                  \
  __builtin_amdgcn_global_load_lds(                                            \
      (__attribute__((address_space(1))) void*)(void*)(gp_),                   \
      (__attribute__((address_space(3))) void*)(lp_), 16, 0, 17)

__global__ void prep1(const float* __restrict__ x,
                      const float* __restrict__ h0,
                      float* __restrict__ ws) {
  int i = blockIdx.x * blockDim.x + threadIdx.x;
  const int stride = gridDim.x * blockDim.x;
  const int NXT = 512 * 512;
  const int NTH0 = 32 * 3072;
  const int NBAR = 4608;
  for (; i < NXT + NTH0 + NBAR; i += stride) {
    if (i < NXT) {
      int t = i >> 9, bi = i & 511;
      ws[XT_OFF + i] = x[bi * 512 + t];
    } else if (i < NXT + NTH0) {
      int e = i - NXT;
      int b = e / 3072, n = e - b * 3072;
      float v = tanhf(h0[e]);
      ws[THBUF_OFF + e] = v;
      ws[THT_OFF + n * 32 + b] = v;
    } else {
      ((unsigned*)(ws + BAR_OFF))[i - (NXT + NTH0)] = 0u;
    }
  }
}

__global__ void prep2(const float* __restrict__ iwn,
                      float* __restrict__ ws) {
  int n = blockIdx.x * blockDim.x + threadIdx.x;
  if (n >= 3072) return;
  const float s10 = sqrtf(10.0f);
  const float a = expf(-0.1f);
  float prev = s10 * iwn[n * 512];
  ws[WN_OFF + n] = 0.01f * prev;
  for (int t = 1; t < 512; ++t) {
    float cur = s10 * iwn[n * 512 + t];
    prev = cur + (prev - cur) * a;
    ws[WN_OFF + t * 3072 + n] = 0.01f * prev;
  }
}

// Fence-free flag barrier (unchanged from R5).
__device__ __forceinline__ void flagBarrier(unsigned* flags, unsigned* gen,
                                            int g, int tid, unsigned tv) {
  asm volatile("s_waitcnt vmcnt(0)" ::: "memory");
  __syncthreads();
  if (tid == 0)
    __hip_atomic_store(&flags[g * 16], tv, __ATOMIC_RELAXED, __HIP_MEMORY_SCOPE_AGENT);
  if (g == MASTER) {
    while (__hip_atomic_load(&flags[tid * 16], __ATOMIC_RELAXED,
                             __HIP_MEMORY_SCOPE_AGENT) < tv)
      __builtin_amdgcn_s_sleep(1);
    __syncthreads();
    if (tid < 32)
      __hip_atomic_store(&gen[tid * 16], tv, __ATOMIC_RELAXED, __HIP_MEMORY_SCOPE_AGENT);
  } else {
    if (tid == 0) {
      while (__hip_atomic_load(&gen[(g >> 3) * 16], __ATOMIC_RELAXED,
                               __HIP_MEMORY_SCOPE_AGENT) < tv)
        __builtin_amdgcn_s_sleep(1);
    }
    __syncthreads();
  }
}

// Stage one 32x256 th chunk into LDS half ((c)&1), with quad-granular
// k-rotation per row (rho = row>>3): LDS stays linear (gload_lds requirement);
// the SOURCE address is pre-swizzled so LDS col c holds global k where
// c = (k&~31)|((k+4*rho)&31)  [both-sides-or-neither rule, m173/m228c].
#define LOADPF_LDS(c_) do {                                                    \
  const float* src_ = thmod + (c_) * 256;                                      \
  float* dsth_ = th_base + (((c_) & 1) ? 8320 : 0);                            \
  _Pragma("unroll")                                                            \
  for (int i_ = 0; i_ < 8; ++i_) {                                             \
    int row_ = i_ * 4 + wv;                                                    \
    int rho4_ = (row_ >> 3) * 4;                                               \
    int k0_ = (lane16 & ~31) | ((lane16 - rho4_) & 31);                        \
    GLOAD_LDS16(src_ + (size_t)row_ * 3072 + k0_, dsth_ + row_ * 260);         \
  } } while (0)

#define DOT4(aj_, ab_, wv_, tv_)                                               \
  accg[(aj_)*4+(ab_)] += wv_.x*tv_.x + wv_.y*tv_.y + wv_.z*tv_.z + wv_.w*tv_.w

// 4x4 register-blocked chunk compute: thread (ksr, jq, bq) accumulates
// j in [jq4,jq4+4) x b in [bq4,bq4+4) over its 32-k slice of this chunk.
// Reads are conflict-free (rotation spreads row-quads across all 32 banks).
#define COMPUTE_CHUNK_RB(c_) do {                                              \
  const float* tb_ = th_base + ((c_) & 1) * 8320;                              \
  const float* t0_ = tb_ + (bq4 + 0) * 260 + ksb;                              \
  const float* t1_ = tb_ + (bq4 + 1) * 260 + ksb;                              \
  const float* t2_ = tb_ + (bq4 + 2) * 260 + ksb;                              \
  const float* t3_ = tb_ + (bq4 + 3) * 260 + ksb;                              \
  const float* w0_ = W_lds + (jq4 + 0) * 1028 + (c_) * 256 + ksb;              \
  const float* w1_ = W_lds + (jq4 + 1) * 1028 + (c_) * 256 + ksb;              \
  const float* w2_ = W_lds + (jq4 + 2) * 1028 + (c_) * 256 + ksb;              \
  const float* w3_ = W_lds + (jq4 + 3) * 1028 + (c_) * 256 + ksb;              \
  _Pragma("unroll")                                                            \
  for (int q_ = 0; q_ < 8; ++q_) {                                             \
    int cw_ = (4 * q_ + rotw) & 31;                                            \
    int ct_ = (4 * q_ + rott) & 31;                                            \
    float4 wv0 = *(const float4*)(w0_ + cw_);                                  \
    float4 wv1 = *(const float4*)(w1_ + cw_);                                  \
    float4 wv2 = *(const float4*)(w2_ + cw_);                                  \
    float4 wv3 = *(const float4*)(w3_ + cw_);                                  \
    float4 tv0 = *(const float4*)(t0_ + ct_);                                  \
    float4 tv1 = *(const float4*)(t1_ + ct_);                                  \
    float4 tv2 = *(const float4*)(t2_ + ct_);                                  \
    float4 tv3 = *(const float4*)(t3_ + ct_);                                  \
    DOT4(0,0,wv0,tv0); DOT4(0,1,wv0,tv1); DOT4(0,2,wv0,tv2); DOT4(0,3,wv0,tv3);\
    DOT4(1,0,wv1,tv0); DOT4(1,1,wv1,tv1); DOT4(1,2,wv1,tv2); DOT4(1,3,wv1,tv3);\
    DOT4(2,0,wv2,tv0); DOT4(2,1,wv2,tv1); DOT4(2,2,wv2,tv2); DOT4(2,3,wv2,tv3);\
    DOT4(3,0,wv3,tv0); DOT4(3,1,wv3,tv1); DOT4(3,2,wv3,tv2); DOT4(3,3,wv3,tv3);\
  } } while (0)

__global__ void __launch_bounds__(256, 1) rnn_main(
    const float* __restrict__ Wih,
    const float* __restrict__ W11,
    const float* __restrict__ W22,
    const float* __restrict__ W33,
    const float* __restrict__ W12,
    const float* __restrict__ W23,
    const float* __restrict__ Who,
    const float* __restrict__ Whc2,
    const float* __restrict__ Wr1,
    const float* __restrict__ Wr2,
    const float* __restrict__ Wr3,
    const int* __restrict__ id12_1, const int* __restrict__ id12_2,
    const int* __restrict__ id23_2, const int* __restrict__ id23_3,
    const float* __restrict__ ctx,
    const float* __restrict__ h0,
    float* __restrict__ ws,
    float* __restrict__ out) {

  extern __shared__ float smem[];
  float* W_lds   = smem + L_W;
  float* th_base = smem + L_TH;
  float* coupf   = smem + L_COUP;
  float* Wih_lds = smem + L_WIH;
  float* Hbuf    = smem + L_HBUF;
  float* thcur   = smem + L_RED + 512;
  float* ci16    = smem + L_CI;
  int* gidx_lds  = (int*)(smem + L_GIDX);
  int* ql_j      = (int*)(smem + L_QLJ);
  int* ql_q      = (int*)(smem + L_QLQ);
  int* nq_sp     = (int*)(smem + L_NQ);

  const int g = blockIdx.x;
  const int tid = threadIdx.x;
  unsigned* flags = (unsigned*)(ws + BAR_OFF);
  unsigned* gen = flags + 4096;
  const int mmod = (g < 192) ? (g >> 6) : 0;
  const int loc0 = (g & 63) * 16;
  const int bb = tid & 15;
  const int jg = (tid >> 4) & 7;
  const int kh = tid >> 7;
  const int wv = tid >> 6;           // wave id
  const int lane16 = (tid & 63) * 4; // 16B lane offset (floats)
  // 4x4 register-blocking thread map
  const int ksr  = tid >> 5;           // 0..7 K-slice
  const int ksb  = ksr * 32;
  const int jq4  = ((tid >> 3) & 3) * 4;
  const int bq4  = (tid & 7) * 4;
  const int rotw = ((tid >> 4) & 1) * 4;  // (jq>>1)&1 * 4
  const int rott = ((tid >> 1) & 3) * 4;  // (bq>>1)   * 4
  float h00 = 0.f, h01 = 0.f, h10 = 0.f, h11 = 0.f;

  if (g < 192) {
    const float* Wsrc = (mmod == 0) ? W11 : ((mmod == 1) ? W22 : W33);
    // stage W slice (16 x 1024 fp32) into LDS once, k-rotated per row
    #pragma unroll
    for (int i = 0; i < 16; ++i) {
      float4 v = *(const float4*)&Wsrc[(size_t)(loc0 + i) * 1024 + tid * 4];
      int k = tid * 4;
      int rw4 = ((i >> 3) & 1) * 4;
      int cst = (k & ~31) | ((k + rw4) & 31);
      *(float4*)&W_lds[i * 1028 + cst] = v;
    }
    if (mmod == 0) {
      Wih_lds[tid] = Wih[(loc0 + (tid >> 4)) * 16 + (tid & 15)];
    }
    if (mmod == 1 && tid < 16) {
      ci16[tid] = ctx[0] * Whc2[(loc0 + tid) * 2];
    }
    if (mmod != 0 && tid < 205) {
      const int* gsrc = (mmod == 1) ? id12_1 : id23_2;
      gidx_lds[tid] = gsrc[tid];
    }
    if (tid == 0) {
      int cnt = 0;
      if (mmod != 0) {
        const int* scat = (mmod == 1) ? id12_2 : id23_3;
        for (int q = 0; q < 205; ++q) {
          int jj = scat[q] - loc0;
          if (jj >= 0 && jj < 16) { ql_j[cnt] = jj; ql_q[cnt] = q; ++cnt; }
        }
      }
      *nq_sp = cnt;
    }
    if (!kh) {
      int gn0 = mmod * 1024 + loc0 + jg;
      h00 = h0[bb * 3072 + gn0];
      h01 = h0[(bb + 16) * 3072 + gn0];
      h10 = h0[bb * 3072 + gn0 + 8];
      h11 = h0[(bb + 16) * 3072 + gn0 + 8];
    }
  }
  __syncthreads();

  #pragma unroll 1
  for (int t = 0; t < 512; ++t) {
    const int p = t & 1;
    const float* thbuf_p = ws + THBUF_OFF + (size_t)p * 98304;
    float*       thbuf_n = ws + THBUF_OFF + (size_t)(p ^ 1) * 98304;
    const float* thT_p   = ws + THT_OFF + (size_t)p * 98304;
    float*       thT_n   = ws + THT_OFF + (size_t)(p ^ 1) * 98304;

    if (g < 192) {
      const float* thmod = thbuf_p + mmod * 1024;
      float* thsp = th_base + 8320;  // sparse gather buf (half1 of th_base)
      // zero coupling staging
      *(float4*)&coupf[tid * 4] = make_float4(0.f, 0.f, 0.f, 0.f);
      // ---- sparse gather: 7 coherent 16B LDS-direct loads/thread ----
      if (mmod != 0) {
        const int rbase = (mmod == 1) ? 0 : 1024;
        #pragma unroll
        for (int i = 0; i < 7; ++i) {
          int e = tid + i * 256;
          if (e > 1639) e = 1639;
          int pp = e >> 3, bq = (e & 7) * 4;
          GLOAD_LDS16(&thT_p[(size_t)(rbase + gidx_lds[pp]) * 32 + bq],
                      thsp + 4 * (i * 256 + wv * 64));
        }
      }
      // ---- prefetch GEMM chunk 0 into half0 (swizzled source) ----
      LOADPF_LDS(0);
      __syncthreads();   // vmcnt drained by compiler: thsp + half0 ready
      // ---- sparse coupling: dot products from LDS ----
      if (mmod != 0) {
        const int ntask = *nq_sp * 64;
        const float* Wsp = (mmod == 1) ? W12 : W23;
        for (int task = tid; task < ntask; task += 256) {
          int kh2 = task & 1;
          int b = (task >> 1) & 31;
          int qi = task >> 6;
          int q = ql_q[qi], jj = ql_j[qi];
          int p0 = kh2 ? 103 : 0;
          int p1 = kh2 ? 205 : 103;
          float v = 0.0f;
          for (int pp = p0; pp < p1; ++pp) {
            v += Wsp[q * 205 + pp] * thsp[pp * 32 + b];
          }
          coupf[kh2 * 512 + jj * 32 + b] = v;
        }
      }
      __syncthreads();   // thsp free (chunk1 will overwrite half1)
      // ---- main GEMM: 4x4 register blocking, K split 8-way ----
      float accg[16];
      #pragma unroll
      for (int i = 0; i < 16; ++i) accg[i] = 0.f;
      #pragma unroll 1
      for (int c = 0; c < 4; ++c) {
        if (c < 3) LOADPF_LDS(c + 1);   // into the half freed at last barrier
        COMPUTE_CHUNK_RB(c);
        __syncthreads();                // chunk c+1 landed; half c&1 freed
      }
      // ---- K-partial reduction via LDS (record stride 13 spreads banks) ----
      float* red2 = th_base;            // 512*13 = 6656 floats (half0 free now)
      #pragma unroll
      for (int dj = 0; dj < 4; ++dj)
        #pragma unroll
        for (int db = 0; db < 4; ++db) {
          int cell = (jq4 + dj) * 32 + bq4 + db;
          red2[cell * 13 + ksr] = accg[dj * 4 + db];
        }
      __syncthreads();
      if (!kh) {
        float accs[4];
        #pragma unroll
        for (int js = 0; js < 2; ++js)
          #pragma unroll
          for (int bs = 0; bs < 2; ++bs) {
            int cell = (jg + 8 * js) * 32 + bb + 16 * bs;
            float s = 0.f;
            #pragma unroll
            for (int k8 = 0; k8 < 8; ++k8) s += red2[cell * 13 + k8];
            accs[js * 2 + bs] = s;
          }
        const float* xTt = ws + XT_OFF + t * 512;
        const float* wnt = ws + WN_OFF + t * 3072;
        float hs[4] = {h00, h01, h10, h11};
        #pragma unroll
        for (int js = 0; js < 2; ++js) {
          int j = jg + js * 8;
          int gn = mmod * 1024 + loc0 + j;
          #pragma unroll
          for (int bs = 0; bs < 2; ++bs) {
            int b = bb + bs * 16;
            float dot = accs[js * 2 + bs];
            float extra;
            if (mmod == 0) {
              extra = 0.f;
              #pragma unroll
              for (int ii = 0; ii < 16; ++ii)
                extra += xTt[b * 16 + ii] * Wih_lds[j * 16 + ii];
            } else {
              float cp = coupf[j * 32 + b] + coupf[512 + j * 32 + b];
              extra = (mmod == 1) ? cp * ci16[j] : cp;
            }
            float hv = hs[js * 2 + bs];
            hv = hv + (dot + extra + wnt[gn] - hv) / 10.0f;
            hs[js * 2 + bs] = hv;
            float tv = tanhf(hv);
            thcur[j * 32 + b] = tv;               // LDS staging for wide stores
            Hbuf[(j * 32 + b) * 4 + (t & 3)] = tv;
          }
        }
        h00 = hs[0]; h01 = hs[1]; h10 = hs[2]; h11 = hs[3];
      }
      __syncthreads();
      // ---- publish th with ONE 16B write-through store per thread ----
      {
        const int base = mmod * 1024 + loc0;
        if (tid < 128) {
          int b = tid & 31, q = tid >> 5;
          float4 v;
          v.x = thcur[(4 * q + 0) * 32 + b];
          v.y = thcur[(4 * q + 1) * 32 + b];
          v.z = thcur[(4 * q + 2) * 32 + b];
          v.w = thcur[(4 * q + 3) * 32 + b];
          stc_f4(&thbuf_n[(size_t)b * 3072 + base + 4 * q], v);
        } else {
          int u = tid - 128;
          int j = u >> 3, vq = u & 7;
          float4 v = *(const float4*)&thcur[j * 32 + 4 * vq];
          stc_f4(&thT_n[(size_t)(base + j) * 32 + 4 * vq], v);
        }
      }
      if ((t & 3) == 3) {
        __syncthreads();
        #pragma unroll
        for (int r = 0; r < 2; ++r) {
          int o = tid * 2 + r;
          int j = o >> 5, b = o & 31;
          size_t gn = (size_t)(mmod * 1024 + loc0 + j);
          float4 v = *(const float4*)&Hbuf[o * 4];
          nt_store_f4(&out[((size_t)b * 3072 + gn) * 512 + (t - 3)], v);
        }
      }
    } else {
      // ---- aux WGs: y and yr readouts ----
      const int w = tid >> 6, lane = tid & 63;
      const int gw = (g - 192) * 4 + w;
      float* auxb = coupf;            // aux-only alias
      float* stg = W_lds + w * 1024;  // per-wave 4x256 staging (W_lds unused here)
      for (int s = 0; s < 4; ++s) {
        const int u = gw + s * 256;
        if (u >= 800) break;
        float a0 = 0.f, a1 = 0.f, a2 = 0.f, a3 = 0.f;
        if (u < 768) {
          const int mm = u >> 8;
          const int rem = u & 255;
          const int b = rem >> 3;
          const int rr0 = (rem & 7) * 4;
          const float* Wr = (mm == 0) ? Wr1 : ((mm == 1) ? Wr2 : Wr3);
          const float* trow = thbuf_p + b * 3072 + mm * 1024;
          #pragma unroll
          for (int it = 0; it < 4; ++it)
            GLOAD_LDS16(trow + it * 256 + lane * 4, stg + it * 256);
          asm volatile("s_waitcnt vmcnt(0)" ::: "memory");
          __builtin_amdgcn_sched_barrier(0);
          #pragma unroll
          for (int it = 0; it < 4; ++it) {
            int k = it * 256 + lane * 4;
            float4 tv = *(const float4*)&stg[it * 256 + lane * 4];
            float4 q0 = *(const float4*)&Wr[(rr0 + 0) * 1024 + k];
            float4 q1 = *(const float4*)&Wr[(rr0 + 1) * 1024 + k];
            float4 q2 = *(const float4*)&Wr[(rr0 + 2) * 1024 + k];
            float4 q3 = *(const float4*)&Wr[(rr0 + 3) * 1024 + k];
            a0 += tv.x*q0.x + tv.y*q0.y + tv.z*q0.z + tv.w*q0.w;
            a1 += tv.x*q1.x + tv.y*q1.y + tv.z*q1.z + tv.w*q1.w;
            a2 += tv.x*q2.x + tv.y*q2.y + tv.z*q2.z + tv.w*q2.w;
            a3 += tv.x*q3.x + tv.y*q3.y + tv.z*q3.z + tv.w*q3.w;
          }
          __builtin_amdgcn_sched_barrier(0);
        } else {
          const int b = u - 768;
          const float* trow = thbuf_p + b * 3072 + 2048;
          #pragma unroll
          for (int it = 0; it < 4; ++it)
            GLOAD_LDS16(trow + it * 256 + lane * 4, stg + it * 256);
          asm volatile("s_waitcnt vmcnt(0)" ::: "memory");
          __builtin_amdgcn_sched_barrier(0);
          #pragma unroll
          for (int it = 0; it < 4; ++it) {
            int k = it * 256 + lane * 4;
            float4 tv = *(const float4*)&stg[it * 256 + lane * 4];
            float4 q0 = *(const float4*)&Who[k];
            a0 += tv.x*q0.x + tv.y*q0.y + tv.z*q0.z + tv.w*q0.w;
          }
          __builtin_amdgcn_sched_barrier(0);
        }
        #pragma unroll
        for (int off = 32; off > 0; off >>= 1) {
          a0 += __shfl_xor(a0, off);
          a1 += __shfl_xor(a1, off);
          a2 += __shfl_xor(a2, off);
          a3 += __shfl_xor(a3, off);
        }
        if (lane == 0) {
          int base = ((w * 4 + s) * 4) * 4 + (t & 3);
          auxb[base] = tanhf(a0);
          if (u < 768) {
            auxb[base + 4]  = tanhf(a1);
            auxb[base + 8]  = tanhf(a2);
            auxb[base + 12] = tanhf(a3);
          }
        }
      }
      if ((t & 3) == 3) {
        __syncthreads();
        int s = lane >> 2, rv = lane & 3;
        if (lane < 16) {
          int u = gw + s * 256;
          if (u < 768) {
            int mm = u >> 8, rem = u & 255, b = rem >> 3, rr = (rem & 7) * 4 + rv;
            float4 v = *(const float4*)&auxb[((w * 4 + s) * 4 + rv) * 4];
            nt_store_f4(&out[(size_t)YR0_OFF + ((size_t)(b * 32 + rr) * 3 + mm) * 512 + (t - 3)], v);
          } else if (u < 800 && rv == 0) {
            float4 v = *(const float4*)&auxb[((w * 4 + s) * 4) * 4];
            nt_store_f4(&out[(size_t)Y0_OFF + (size_t)(u - 768) * 512 + (t - 3)], v);
          }
        }
      }
    }
    flagBarrier(flags, gen, g, tid, (unsigned)(t + 1));
  }
}

extern "C" void kernel_launch(void* const* d_in, const int* in_sizes, int n_in,
                              void* d_out, int out_size, void* d_ws, size_t ws_size,
                              hipStream_t stream) {
  (void)in_sizes; (void)n_in; (void)out_size; (void)ws_size;
  const float* x    = (const float*)d_in[0];
  const float* h0   = (const float*)d_in[1];
  const float* ctx  = (const float*)d_in[2];
  const float* iWN  = (const float*)d_in[3];
  const float* Wih  = (const float*)d_in[4];
  const float* W11  = (const float*)d_in[5];
  const float* W22  = (const float*)d_in[6];
  const float* W33  = (const float*)d_in[7];
  const float* W12  = (const float*)d_in[8];
  const float* W23  = (const float*)d_in[9];
  const float* Who  = (const float*)d_in[10];
  const float* Whc2 = (const float*)d_in[11];
  const float* Wr1  = (const float*)d_in[12];
  const float* Wr2  = (const float*)d_in[13];
  const float* Wr3  = (const float*)d_in[14];
  const int* id12_1 = (const int*)d_in[15];
  const int* id12_2 = (const int*)d_in[16];
  const int* id23_2 = (const int*)d_in[17];
  const int* id23_3 = (const int*)d_in[18];
  float* ws = (float*)d_ws;
  float* out = (float*)d_out;

  hipFuncSetAttribute(reinterpret_cast<const void*>(rnn_main),
                      hipFuncAttributeMaxDynamicSharedMemorySize, SMEM_BYTES);
  hipLaunchKernelGGL(prep1, dim3(512), dim3(256), 0, stream, x, h0, ws);
  hipLaunchKernelGGL(prep2, dim3(12), dim3(256), 0, stream, iWN, ws);
  hipLaunchKernelGGL(rnn_main, dim3(256), dim3(256), SMEM_BYTES, stream,
                     Wih, W11, W22, W33, W12, W23, Who, Whc2, Wr1, Wr2, Wr3,
                     id12_1, id12_2, id23_2, id23_3, ctx, h0, ws, out);
}